// Round 1
// baseline (517.316 us; speedup 1.0000x reference)
//
#include <hip/hip_runtime.h>
#include <hip/hip_bf16.h>
#include <stdint.h>

#define NWIN 216      // 6^3 windows
#define NVOX 110592   // 48^3

typedef __bf16 bf16_t;
typedef __attribute__((ext_vector_type(8))) __bf16 bf16x8;
typedef __attribute__((ext_vector_type(4))) float f32x4;
typedef __attribute__((ext_vector_type(4))) unsigned int u32x4;

__device__ __forceinline__ f32x4 mfma16(bf16x8 a, bf16x8 b, f32x4 c) {
  return __builtin_amdgcn_mfma_f32_16x16x32_bf16(a, b, c, 0, 0, 0);
}

__device__ __forceinline__ unsigned int pk2(float lo, float hi) {
  unsigned short l = __builtin_bit_cast(unsigned short, (bf16_t)lo);
  unsigned short h = __builtin_bit_cast(unsigned short, (bf16_t)hi);
  return (unsigned int)l | ((unsigned int)h << 16);
}

// ---------------- Kernel 1: QKV 1x1x1 conv + window gather ----------------
// qkv layout: [3][216][4][512][32] bf16; q pre-scaled by log2(e)/sqrt(32)
__global__ __launch_bounds__(256, 1) void qkv_kernel(const float* __restrict__ x,
                                                     const float* __restrict__ w_qkv,
                                                     bf16_t* __restrict__ qkv) {
  __shared__ bf16_t xs[64][520];   // [c][n]  66.6 KB
  __shared__ bf16_t wsm[384][72];  // [o][c]  55.3 KB
  const int w = blockIdx.x;
  const int wx = w / 36, wy = (w / 6) % 6, wz = w % 6;
  const int t = threadIdx.x;
  const int lane = t & 63;
  const int q16 = lane & 15, g = lane >> 4;
  const float SC = 0.25505003946337226f;  // log2(e)/sqrt(32)

  // stage w_qkv -> bf16 LDS [o][c]
  #pragma unroll
  for (int i = 0; i < 24; ++i) {
    int seg = t + 256 * i;               // 6144 segs of 4 floats
    int o = seg >> 4, cq = (seg & 15) << 2;
    float4 v4 = reinterpret_cast<const float4*>(w_qkv)[seg];
    float sc = (o < 128) ? SC : 1.0f;
    bf16_t* dst = &wsm[o][cq];
    dst[0] = (bf16_t)(v4.x * sc); dst[1] = (bf16_t)(v4.y * sc);
    dst[2] = (bf16_t)(v4.z * sc); dst[3] = (bf16_t)(v4.w * sc);
  }
  // stage x window -> bf16 LDS [c][n] (n = ix*64 + iy*8 + iz)
  #pragma unroll
  for (int i = 0; i < 16; ++i) {
    int seg = t + 256 * i;               // 4096 segs: (c, ix, iy) x 8 z
    int c = seg >> 6, ixy = seg & 63;
    const float* src = x + (((c * 48 + wx * 8 + (ixy >> 3)) * 48 + wy * 8 + (ixy & 7)) * 48 + wz * 8);
    float4 a = reinterpret_cast<const float4*>(src)[0];
    float4 b = reinterpret_cast<const float4*>(src)[1];
    bf16_t* dst = &xs[c][ixy * 8];
    dst[0]=(bf16_t)a.x; dst[1]=(bf16_t)a.y; dst[2]=(bf16_t)a.z; dst[3]=(bf16_t)a.w;
    dst[4]=(bf16_t)b.x; dst[5]=(bf16_t)b.y; dst[6]=(bf16_t)b.z; dst[7]=(bf16_t)b.w;
  }
  __syncthreads();

  const int wv = t >> 6;                 // wave id: owns o-tiles wv*6 .. wv*6+5
  bf16x8 bw[6][2];                       // B = W^T[c][o]: lane col o=lane%16, c=8*(lane/16)+e
  #pragma unroll
  for (int j = 0; j < 6; ++j)
    #pragma unroll
    for (int s = 0; s < 2; ++s)
      bw[j][s] = *(const bf16x8*)&wsm[wv * 96 + j * 16 + q16][s * 32 + 8 * g];

  for (int nt = 0; nt < 32; ++nt) {
    int n = nt * 16 + q16;
    bf16x8 a0, a1;                       // A = X^T[n][c]: lane row n=lane%16, c=8*(lane/16)+e
    #pragma unroll
    for (int e = 0; e < 8; ++e) {
      a0[e] = xs[8 * g + e][n];
      a1[e] = xs[32 + 8 * g + e][n];
    }
    #pragma unroll
    for (int j = 0; j < 6; ++j) {
      f32x4 acc = {0.f, 0.f, 0.f, 0.f};
      acc = mfma16(a0, bw[j][0], acc);
      acc = mfma16(a1, bw[j][1], acc);
      // D: col = o-local = lane&15, row = n-local = 4*(lane>>4)+r
      int o = wv * 96 + j * 16 + q16;
      int sel = o >> 7, rem = o & 127, hh = rem >> 5, dd = rem & 31;
      size_t base = ((((size_t)sel * NWIN + w) * 4 + hh) * 512 + nt * 16 + 4 * g) * 32 + dd;
      #pragma unroll
      for (int r = 0; r < 4; ++r)
        qkv[base + (size_t)r * 32] = (bf16_t)acc[r];
    }
  }
}

// ---------------- Kernel 2: windowed attention, one (window, head) per block ----------------
// att layout: [216][512][128] bf16 (hc = h*32 + d)
__global__ __launch_bounds__(256, 2) void attn_kernel(const bf16_t* __restrict__ qkv,
                                                      bf16_t* __restrict__ att) {
  __shared__ bf16_t kls[512][40];   // K [n][d], padded     40 KB
  __shared__ bf16_t vt[32][520];    // V^T [d][n], padded   32.5 KB
  const int blk = blockIdx.x;
  const int w = blk >> 2, h = blk & 3;
  const bf16_t* qb = qkv + ((size_t)(0 * NWIN + w) * 4 + h) * 16384;
  const bf16_t* kb = qkv + ((size_t)(1 * NWIN + w) * 4 + h) * 16384;
  const bf16_t* vb = qkv + ((size_t)(2 * NWIN + w) * 4 + h) * 16384;
  const int t = threadIdx.x, lane = t & 63, wv = t >> 6;
  const int q16 = lane & 15, g = lane >> 4;

  #pragma unroll
  for (int i = 0; i < 8; ++i) {
    int seg = t + 256 * i;             // 2048 segs of 8 bf16
    int n = seg >> 2, d = (seg & 3) * 8;
    *(bf16x8*)&kls[n][d] = *(const bf16x8*)(kb + n * 32 + d);
    bf16x8 vv = *(const bf16x8*)(vb + n * 32 + d);
    #pragma unroll
    for (int e = 0; e < 8; ++e) vt[d + e][n] = vv[e];
  }
  __syncthreads();

  for (int ti = 0; ti < 8; ++ti) {
    int qt = wv * 8 + ti;              // q-tile (16 rows); wave owns 8 tiles
    // Q^T B-frag == Q A-frag layout: lane holds q-row lane&15, c = 8*(lane>>4)+e
    bf16x8 qf = *(const bf16x8*)(qb + (qt * 16 + q16) * 32 + 8 * g);
    // Swapped QK^T: S^T tile = mfma(K_rows, Q^T). Lane holds, for q = lane&15,
    // k = kt*16 + 4*(lane>>4) + r   (kt = 0..31, r = 0..3)
    f32x4 st[32];
    #pragma unroll
    for (int kt = 0; kt < 32; ++kt) {
      bf16x8 kf = *(const bf16x8*)&kls[kt * 16 + q16][8 * g];
      f32x4 z = {0.f, 0.f, 0.f, 0.f};
      st[kt] = mfma16(kf, qf, z);
    }
    // softmax over k (scores already include log2e/sqrt(32) via q scaling)
    float m = -1e30f;
    #pragma unroll
    for (int kt = 0; kt < 32; ++kt)
      #pragma unroll
      for (int r = 0; r < 4; ++r) m = fmaxf(m, st[kt][r]);
    m = fmaxf(m, __shfl_xor(m, 16));
    m = fmaxf(m, __shfl_xor(m, 32));
    float sum = 0.f;
    #pragma unroll
    for (int kt = 0; kt < 32; ++kt)
      #pragma unroll
      for (int r = 0; r < 4; ++r) {
        float p = exp2f(st[kt][r] - m);
        st[kt][r] = p;
        sum += p;
      }
    sum += __shfl_xor(sum, 16);
    sum += __shfl_xor(sum, 32);
    float rinv = 1.0f / sum;

    // PV: out[q][d] = P[16q x 32k-chunk] x V[32k x 16d], A-frag built by
    // cvt-pack + xor16/xor48 butterfly (lane g' ends with k = kc*32+8g'+0..7 for its q)
    f32x4 o0 = {0.f,0.f,0.f,0.f}, o1 = {0.f,0.f,0.f,0.f};
    #pragma unroll
    for (int kc = 0; kc < 16; ++kc) {
      unsigned int a0 = pk2(st[2*kc][0],   st[2*kc][1]);
      unsigned int a1 = pk2(st[2*kc][2],   st[2*kc][3]);
      unsigned int b0 = pk2(st[2*kc+1][0], st[2*kc+1][1]);
      unsigned int b1 = pk2(st[2*kc+1][2], st[2*kc+1][3]);
      unsigned int pa0 = __shfl_xor(a0, 16), pa1 = __shfl_xor(a1, 16);
      unsigned int pb0 = __shfl_xor(b0, 16), pb1 = __shfl_xor(b1, 16);
      const bool odd = (g & 1);
      unsigned int ma0 = odd ? pa0 : a0, ma1 = odd ? pa1 : a1;
      unsigned int ma2 = odd ? a0 : pa0, ma3 = odd ? a1 : pa1;
      unsigned int mb0 = odd ? pb0 : b0, mb1 = odd ? pb1 : b1;
      unsigned int mb2 = odd ? b0 : pb0, mb3 = odd ? b1 : pb1;
      // g=1 holds frag2 in mb (send to g=2); g=2 holds frag1 in ma (send to g=1)
      unsigned int s0 = (g == 1) ? mb0 : ma0, s1 = (g == 1) ? mb1 : ma1;
      unsigned int s2 = (g == 1) ? mb2 : ma2, s3 = (g == 1) ? mb3 : ma3;
      unsigned int r0 = __shfl_xor(s0, 48), r1 = __shfl_xor(s1, 48);
      unsigned int r2 = __shfl_xor(s2, 48), r3 = __shfl_xor(s3, 48);
      unsigned int f0 = (g == 0) ? ma0 : ((g == 3) ? mb0 : r0);
      unsigned int f1 = (g == 0) ? ma1 : ((g == 3) ? mb1 : r1);
      unsigned int f2 = (g == 0) ? ma2 : ((g == 3) ? mb2 : r2);
      unsigned int f3 = (g == 0) ? ma3 : ((g == 3) ? mb3 : r3);
      u32x4 uf = {f0, f1, f2, f3};
      bf16x8 af = __builtin_bit_cast(bf16x8, uf);
      bf16x8 v0 = *(const bf16x8*)&vt[q16][kc * 32 + 8 * g];
      bf16x8 v1 = *(const bf16x8*)&vt[16 + q16][kc * 32 + 8 * g];
      o0 = mfma16(af, v0, o0);
      o1 = mfma16(af, v1, o1);
    }
    // D: col = d = lane&15 (+16 for o1), row = q-local = 4g + r. rinv lives at lanes
    // with (lane&15) == q-row; fetch per r.
    #pragma unroll
    for (int r = 0; r < 4; ++r) {
      float ri = __shfl(rinv, (lane & 48) + 4 * g + r, 64);
      int n = qt * 16 + 4 * g + r;
      size_t ob = ((size_t)w * 512 + n) * 128 + h * 32;
      att[ob + q16]      = (bf16_t)(o0[r] * ri);
      att[ob + 16 + q16] = (bf16_t)(o1[r] * ri);
    }
  }
}

// ---------------- Kernel 3: merge-heads 1x1x1 conv (fp32 VALU) ----------------
__global__ __launch_bounds__(256, 2) void proj_kernel(const bf16_t* __restrict__ att,
                                                      const float* __restrict__ w_out,
                                                      const float* __restrict__ b_out,
                                                      float* __restrict__ out) {
  int v = blockIdx.x * 256 + threadIdx.x;
  int gz = v % 48, gy = (v / 48) % 48, gx = v / 2304;
  int w = (gx >> 3) * 36 + (gy >> 3) * 6 + (gz >> 3);
  int n = ((gx & 7) << 6) + ((gy & 7) << 3) + (gz & 7);
  const bf16_t* arow = att + ((size_t)w * 512 + n) * 128;
  float a[128];
  #pragma unroll
  for (int i = 0; i < 16; ++i) {
    bf16x8 v8 = *(const bf16x8*)(arow + i * 8);
    #pragma unroll
    for (int e = 0; e < 8; ++e) a[i * 8 + e] = (float)v8[e];
  }
  for (int o = 0; o < 64; ++o) {
    const float* wr = w_out + o * 128;   // uniform -> scalar loads
    float s0 = 0.f, s1 = 0.f, s2 = 0.f, s3 = 0.f;
    #pragma unroll
    for (int hc = 0; hc < 128; hc += 4) {
      s0 += a[hc]     * wr[hc];
      s1 += a[hc + 1] * wr[hc + 1];
      s2 += a[hc + 2] * wr[hc + 2];
      s3 += a[hc + 3] * wr[hc + 3];
    }
    out[(size_t)o * NVOX + v] = (s0 + s1) + (s2 + s3) + b_out[o];
  }
}

extern "C" void kernel_launch(void* const* d_in, const int* in_sizes, int n_in,
                              void* d_out, int out_size, void* d_ws, size_t ws_size,
                              hipStream_t stream) {
  const float* x     = (const float*)d_in[0];
  const float* w_qkv = (const float*)d_in[1];
  const float* w_out = (const float*)d_in[2];
  const float* b_out = (const float*)d_in[3];
  float* out = (float*)d_out;
  // ws: qkv bf16 [3][216][4][512][32] = 84,934,656 B; att bf16 [216][512][128] = 28,311,552 B
  bf16_t* qkv = (bf16_t*)d_ws;
  bf16_t* att = (bf16_t*)((char*)d_ws + (size_t)3 * NWIN * 4 * 512 * 32 * 2);
  qkv_kernel<<<dim3(NWIN), dim3(256), 0, stream>>>(x, w_qkv, qkv);
  attn_kernel<<<dim3(NWIN * 4), dim3(256), 0, stream>>>(qkv, att);
  proj_kernel<<<dim3(NVOX / 256), dim3(256), 0, stream>>>(att, w_out, b_out, out);
}